// Round 4
// baseline (500.357 us; speedup 1.0000x reference)
//
#include <hip/hip_runtime.h>

#define B_DIM 8
#define S_LEN 4096
#define D_DIM 512
#define H_DIM 512

#define DECAY_F 0.90483743f   // exp(-0.1)
#define ALPHA_F 0.01f
#define EPS_F   1e-6f

// ---------------- GEMM: h[m][n] = sum_k x[m][k] * W[n][k] + bias[n] ----------------
// 128x128 tile, KT=16, 8x8/thread, double-buffered LDS (1 barrier per K-tile).
// Per-element k-accumulation order identical to R2/R3 -> bit-identical h.
#define KT 16
__global__ __launch_bounds__(256) void gemm_kernel(const float* __restrict__ x,
                                                   const float* __restrict__ W,
                                                   const float* __restrict__ bias,
                                                   float* __restrict__ out) {
    __shared__ float As[2][KT][132];
    __shared__ float Bs[2][KT][132];

    const int tid = threadIdx.x;
    const int tx = tid & 15;     // n sub-tile 0..15
    const int ty = tid >> 4;     // m sub-tile 0..15
    const int bm = blockIdx.y * 128;
    const int bn = blockIdx.x * 128;

    const int lrow = tid >> 2;          // 0..63
    const int lk4  = (tid & 3) * 4;     // 0,4,8,12

    const float* xa = &x[(size_t)(bm + lrow) * D_DIM + lk4];
    const float* xb = &x[(size_t)(bm + lrow + 64) * D_DIM + lk4];
    const float* wa = &W[(size_t)(bn + lrow) * D_DIM + lk4];
    const float* wb = &W[(size_t)(bn + lrow + 64) * D_DIM + lk4];

    float acc[8][8];
#pragma unroll
    for (int i = 0; i < 8; ++i)
#pragma unroll
        for (int j = 0; j < 8; ++j) acc[i][j] = 0.f;

    // stage tile 0 -> regs -> LDS[0]
    float4 a0 = *reinterpret_cast<const float4*>(xa);
    float4 a1 = *reinterpret_cast<const float4*>(xb);
    float4 b0 = *reinterpret_cast<const float4*>(wa);
    float4 b1 = *reinterpret_cast<const float4*>(wb);

#define WRITE_LDS(BUF)                                             \
    do {                                                           \
        As[BUF][lk4 + 0][lrow]      = a0.x;                        \
        As[BUF][lk4 + 1][lrow]      = a0.y;                        \
        As[BUF][lk4 + 2][lrow]      = a0.z;                        \
        As[BUF][lk4 + 3][lrow]      = a0.w;                        \
        As[BUF][lk4 + 0][lrow + 64] = a1.x;                        \
        As[BUF][lk4 + 1][lrow + 64] = a1.y;                        \
        As[BUF][lk4 + 2][lrow + 64] = a1.z;                        \
        As[BUF][lk4 + 3][lrow + 64] = a1.w;                        \
        Bs[BUF][lk4 + 0][lrow]      = b0.x;                        \
        Bs[BUF][lk4 + 1][lrow]      = b0.y;                        \
        Bs[BUF][lk4 + 2][lrow]      = b0.z;                        \
        Bs[BUF][lk4 + 3][lrow]      = b0.w;                        \
        Bs[BUF][lk4 + 0][lrow + 64] = b1.x;                        \
        Bs[BUF][lk4 + 1][lrow + 64] = b1.y;                        \
        Bs[BUF][lk4 + 2][lrow + 64] = b1.z;                        \
        Bs[BUF][lk4 + 3][lrow + 64] = b1.w;                        \
    } while (0)

    WRITE_LDS(0);

    // issue loads for tile 1
    a0 = *reinterpret_cast<const float4*>(xa + KT);
    a1 = *reinterpret_cast<const float4*>(xb + KT);
    b0 = *reinterpret_cast<const float4*>(wa + KT);
    b1 = *reinterpret_cast<const float4*>(wb + KT);

    const int NTILE = D_DIM / KT;   // 32
    for (int t = 0; t < NTILE; ++t) {
        const int cur = t & 1;
        __syncthreads();

#pragma unroll
        for (int k = 0; k < KT; ++k) {
            const float4 av0 = *reinterpret_cast<const float4*>(&As[cur][k][ty * 8]);
            const float4 av1 = *reinterpret_cast<const float4*>(&As[cur][k][ty * 8 + 4]);
            const float4 bv0 = *reinterpret_cast<const float4*>(&Bs[cur][k][tx * 8]);
            const float4 bv1 = *reinterpret_cast<const float4*>(&Bs[cur][k][tx * 8 + 4]);
            const float am[8]  = {av0.x, av0.y, av0.z, av0.w, av1.x, av1.y, av1.z, av1.w};
            const float bn_[8] = {bv0.x, bv0.y, bv0.z, bv0.w, bv1.x, bv1.y, bv1.z, bv1.w};
#pragma unroll
            for (int i = 0; i < 8; ++i)
#pragma unroll
                for (int j = 0; j < 8; ++j) acc[i][j] += am[i] * bn_[j];
        }

        if (t + 1 < NTILE) {
            WRITE_LDS(cur ^ 1);
        }
        if (t + 2 < NTILE) {
            const int kk = (t + 2) * KT;
            a0 = *reinterpret_cast<const float4*>(xa + kk);
            a1 = *reinterpret_cast<const float4*>(xb + kk);
            b0 = *reinterpret_cast<const float4*>(wa + kk);
            b1 = *reinterpret_cast<const float4*>(wb + kk);
        }
    }

    const float4 bias0 = *reinterpret_cast<const float4*>(&bias[bn + tx * 8]);
    const float4 bias1 = *reinterpret_cast<const float4*>(&bias[bn + tx * 8 + 4]);
    const float bb[8] = {bias0.x, bias0.y, bias0.z, bias0.w, bias1.x, bias1.y, bias1.z, bias1.w};

#pragma unroll
    for (int i = 0; i < 8; ++i) {
        const size_t row = (size_t)(bm + ty * 8 + i);
        float4 o0, o1;
        o0.x = acc[i][0] + bb[0]; o0.y = acc[i][1] + bb[1];
        o0.z = acc[i][2] + bb[2]; o0.w = acc[i][3] + bb[3];
        o1.x = acc[i][4] + bb[4]; o1.y = acc[i][5] + bb[5];
        o1.z = acc[i][6] + bb[6]; o1.w = acc[i][7] + bb[7];
        *reinterpret_cast<float4*>(&out[row * H_DIM + bn + tx * 8])     = o0;
        *reinterpret_cast<float4*>(&out[row * H_DIM + bn + tx * 8 + 4]) = o1;
    }
}

// ---------------- Scan ----------------
// LDS staging via global_load_lds (no VGPR pressure), double-buffered [2][32][64],
// counted vmcnt waits. Division hand-expanded as LLVM's Newton-Markstein sequence
// with the reciprocal refinement hoisted to the previous step (off the v-critical path).
// Bit-identical to IEEE div for our all-normal operand range (theta in [1,17], |v|<=600).

__device__ __forceinline__ void stage_chunk(const float* __restrict__ gio, float* dstbase,
                                            int c, int lane) {
    // lane l stages row (c*32 + i*4 + (l>>4)), cols (l&15)*4 .. +3.
    // global_load_lds dest = uniform base + lane*16B, which is exactly [step][h] order.
    const float* src = gio + (size_t)(c * 32 + (lane >> 4)) * H_DIM + ((lane & 15) << 2);
#pragma unroll
    for (int i = 0; i < 8; ++i) {
        __builtin_amdgcn_global_load_lds(
            (const __attribute__((address_space(1))) void*)(src + (size_t)i * 4 * H_DIM),
            (__attribute__((address_space(3))) void*)(dstbase + i * 256),
            16, 0, 0);
    }
}

__global__ __launch_bounds__(64, 1) void scan_kernel(float* __restrict__ io,
                                                     float* __restrict__ vout,
                                                     float* __restrict__ thout) {
    __shared__ float sbuf[2][32][64];

    const int lane = threadIdx.x;
    const int bi = blockIdx.x;        // 0..63
    const int b = bi >> 3;            // 0..7
    const int h0 = (bi & 7) << 6;     // 0,64,...,448

    float* gio = io + (size_t)b * S_LEN * H_DIM + h0;

    float v = 0.f;
    float theta = 1.f;
    float tden = theta + EPS_F;
    {
        // refined reciprocal of tden for step 0 (hoisted div front-end)
    }
    float r = __builtin_amdgcn_rcpf(tden);
    float e0 = fmaf(-tden, r, 1.0f);
    float r0 = fmaf(e0, r, r);

    stage_chunk(gio, &sbuf[0][0][0], 0, lane);
    asm volatile("s_waitcnt vmcnt(0)" ::: "memory");

    const int NCHUNK = S_LEN / 32;    // 128
    for (int c = 0; c < NCHUNK; ++c) {
        if (c + 1 < NCHUNK) {
            stage_chunk(gio, &sbuf[(c + 1) & 1][0][0], c + 1, lane);
            // outstanding (issue order): stage(c)=8, stores(c-1)=32, stage(c+1)=8.
            // vmcnt(40) retires the oldest 8 = stage(c). (vmcnt retires in order.)
            asm volatile("s_waitcnt vmcnt(40)" ::: "memory");
        } else {
            // outstanding: stage(c)=8, stores(c-1)=32 -> need <=32.
            asm volatile("s_waitcnt vmcnt(32)" ::: "memory");
        }
        __builtin_amdgcn_sched_barrier(0);

        const float* sb = &sbuf[c & 1][0][0];
        float* gout = gio + (size_t)c * 32 * H_DIM + lane;

#pragma unroll
        for (int u = 0; u < 32; ++u) {
            const float it = sb[u * 64 + lane];
            v = v * DECAY_F + it;
            const float cl = 32.f * theta;          // L * theta * 2
            v = fminf(fmaxf(v, -cl), cl);

            // nv = v / tden, bit-identical IEEE div (Newton-Markstein, normals only):
            const float q0 = v * r0;
            const float e1 = fmaf(-tden, q0, v);
            const float q1 = fmaf(e1, r0, q0);
            const float e2 = fmaf(-tden, q1, v);
            const float nv = fmaf(e2, r0, q1);

            float spike = floorf(nv);
            spike = fminf(fmaxf(spike, 0.f), 16.f);
            v = v - spike * theta;
            theta = theta + ALPHA_F * spike - ALPHA_F * (theta - 1.0f);

            // hoisted reciprocal refinement for NEXT step's division
            tden = theta + EPS_F;
            const float rr = __builtin_amdgcn_rcpf(tden);
            const float ee = fmaf(-tden, rr, 1.0f);
            r0 = fmaf(ee, rr, rr);

            gout[(size_t)u * H_DIM] = spike;
        }
        __builtin_amdgcn_sched_barrier(0);
    }

    const int chain = b * H_DIM + h0 + lane;
    vout[chain]  = v;
    thout[chain] = theta;
}

extern "C" void kernel_launch(void* const* d_in, const int* in_sizes, int n_in,
                              void* d_out, int out_size, void* d_ws, size_t ws_size,
                              hipStream_t stream) {
    const float* x    = (const float*)d_in[0];
    const float* W    = (const float*)d_in[1];
    const float* bias = (const float*)d_in[2];

    float* out   = (float*)d_out;
    float* vout  = out + (size_t)B_DIM * S_LEN * H_DIM;
    float* thout = vout + B_DIM * H_DIM;

    dim3 grid(H_DIM / 128, (B_DIM * S_LEN) / 128);
    gemm_kernel<<<grid, 256, 0, stream>>>(x, W, bias, out);

    scan_kernel<<<64, 64, 0, stream>>>(out, vout, thout);
}

// Round 5
// 479.002 us; speedup vs baseline: 1.0446x; 1.0446x over previous
//
#include <hip/hip_runtime.h>

#define B_DIM 8
#define S_LEN 4096
#define D_DIM 512
#define H_DIM 512

#define DECAY_F 0.90483743f   // exp(-0.1)
#define ALPHA_F 0.01f
#define EPS_F   1e-6f

// ---------------- GEMM: h[m][n] = sum_k x[m][k] * W[n][k] + bias[n] ----------------
// 128x128 tile, KT=16, single-buffer LDS (R3 structure, 204us proven).
// Lane remap: 8x8 thread grid per wave (tr=lane&7, tc=lane>>3), wave tile 64x64.
// => A- and B-reads each have only 8 distinct b128 addresses per wave
//    (8-lane broadcast, 2-way banks = free) -> LDS-pipe no longer the bottleneck.
// Per-element k-accumulation order identical to R2-R4 -> bit-identical h.
#define KT 16
__global__ __launch_bounds__(256, 3) void gemm_kernel(const float* __restrict__ x,
                                                      const float* __restrict__ W,
                                                      const float* __restrict__ bias,
                                                      float* __restrict__ out) {
    __shared__ float As[KT][132];
    __shared__ float Bs[KT][132];

    const int tid = threadIdx.x;
    const int waveId = tid >> 6;
    const int waveR = waveId & 1;        // row half of 128
    const int waveC = waveId >> 1;       // col half of 128
    const int lane = tid & 63;
    const int tr = lane & 7;
    const int tc = lane >> 3;
    const int rbase = waveR * 64 + tr * 8;   // 8 distinct per wave
    const int cbase = waveC * 64 + tc * 8;   // 8 distinct per wave
    const int bm = blockIdx.y * 128;
    const int bn = blockIdx.x * 128;

    const int lrow = tid >> 2;          // 0..63
    const int lk4  = (tid & 3) * 4;     // 0,4,8,12

    const float* xa = &x[(size_t)(bm + lrow) * D_DIM + lk4];
    const float* xb = &x[(size_t)(bm + lrow + 64) * D_DIM + lk4];
    const float* wa = &W[(size_t)(bn + lrow) * D_DIM + lk4];
    const float* wb = &W[(size_t)(bn + lrow + 64) * D_DIM + lk4];

    float acc[8][8];
#pragma unroll
    for (int i = 0; i < 8; ++i)
#pragma unroll
        for (int j = 0; j < 8; ++j) acc[i][j] = 0.f;

    // prologue: stage tile kk=0 into registers
    float4 a0 = *reinterpret_cast<const float4*>(xa);
    float4 a1 = *reinterpret_cast<const float4*>(xb);
    float4 b0 = *reinterpret_cast<const float4*>(wa);
    float4 b1 = *reinterpret_cast<const float4*>(wb);

    for (int kk = 0; kk < D_DIM; kk += KT) {
        __syncthreads();
        As[lk4 + 0][lrow]      = a0.x;
        As[lk4 + 1][lrow]      = a0.y;
        As[lk4 + 2][lrow]      = a0.z;
        As[lk4 + 3][lrow]      = a0.w;
        As[lk4 + 0][lrow + 64] = a1.x;
        As[lk4 + 1][lrow + 64] = a1.y;
        As[lk4 + 2][lrow + 64] = a1.z;
        As[lk4 + 3][lrow + 64] = a1.w;
        Bs[lk4 + 0][lrow]      = b0.x;
        Bs[lk4 + 1][lrow]      = b0.y;
        Bs[lk4 + 2][lrow]      = b0.z;
        Bs[lk4 + 3][lrow]      = b0.w;
        Bs[lk4 + 0][lrow + 64] = b1.x;
        Bs[lk4 + 1][lrow + 64] = b1.y;
        Bs[lk4 + 2][lrow + 64] = b1.z;
        Bs[lk4 + 3][lrow + 64] = b1.w;
        __syncthreads();

        // issue next tile's loads; latency hides under the FMA loop below
        if (kk + KT < D_DIM) {
            a0 = *reinterpret_cast<const float4*>(xa + kk + KT);
            a1 = *reinterpret_cast<const float4*>(xb + kk + KT);
            b0 = *reinterpret_cast<const float4*>(wa + kk + KT);
            b1 = *reinterpret_cast<const float4*>(wb + kk + KT);
        }

#pragma unroll
        for (int k = 0; k < KT; ++k) {
            const float4 av0 = *reinterpret_cast<const float4*>(&As[k][rbase]);
            const float4 av1 = *reinterpret_cast<const float4*>(&As[k][rbase + 4]);
            const float4 bv0 = *reinterpret_cast<const float4*>(&Bs[k][cbase]);
            const float4 bv1 = *reinterpret_cast<const float4*>(&Bs[k][cbase + 4]);
            const float am[8]  = {av0.x, av0.y, av0.z, av0.w, av1.x, av1.y, av1.z, av1.w};
            const float bn_[8] = {bv0.x, bv0.y, bv0.z, bv0.w, bv1.x, bv1.y, bv1.z, bv1.w};
#pragma unroll
            for (int i = 0; i < 8; ++i)
#pragma unroll
                for (int j = 0; j < 8; ++j) acc[i][j] += am[i] * bn_[j];
        }
    }

    const float4 bias0 = *reinterpret_cast<const float4*>(&bias[bn + cbase]);
    const float4 bias1 = *reinterpret_cast<const float4*>(&bias[bn + cbase + 4]);
    const float bb[8] = {bias0.x, bias0.y, bias0.z, bias0.w, bias1.x, bias1.y, bias1.z, bias1.w};

#pragma unroll
    for (int i = 0; i < 8; ++i) {
        const size_t row = (size_t)(bm + rbase + i);
        float4 o0, o1;
        o0.x = acc[i][0] + bb[0]; o0.y = acc[i][1] + bb[1];
        o0.z = acc[i][2] + bb[2]; o0.w = acc[i][3] + bb[3];
        o1.x = acc[i][4] + bb[4]; o1.y = acc[i][5] + bb[5];
        o1.z = acc[i][6] + bb[6]; o1.w = acc[i][7] + bb[7];
        *reinterpret_cast<float4*>(&out[row * H_DIM + bn + cbase])     = o0;
        *reinterpret_cast<float4*>(&out[row * H_DIM + bn + cbase + 4]) = o1;
    }
}

// ---------------- Scan ----------------
// LDS staging via global_load_lds (R4-proven), double-buffered [2][32][64], counted vmcnt.
// New: 8-deep register read-ring (ds_read issued 8 steps = ~350cy before use),
// v_med3 clamps (bit-exact vs fmin(fmax(..)) for our ranges), cl=32*theta and the
// reciprocal refinement hoisted off the v-critical path (computed from prev step's theta).

__device__ __forceinline__ void stage_chunk(const float* __restrict__ gio, float* dstbase,
                                            int c, int lane) {
    const float* src = gio + (size_t)(c * 32 + (lane >> 4)) * H_DIM + ((lane & 15) << 2);
#pragma unroll
    for (int i = 0; i < 8; ++i) {
        __builtin_amdgcn_global_load_lds(
            (const __attribute__((address_space(1))) void*)(src + (size_t)i * 4 * H_DIM),
            (__attribute__((address_space(3))) void*)(dstbase + i * 256),
            16, 0, 0);
    }
}

__global__ __launch_bounds__(64, 1) void scan_kernel(float* __restrict__ io,
                                                     float* __restrict__ vout,
                                                     float* __restrict__ thout) {
    __shared__ float sbuf[2][32][64];

    const int lane = threadIdx.x;
    const int bi = blockIdx.x;        // 0..63
    const int b = bi >> 3;            // 0..7
    const int h0 = (bi & 7) << 6;     // 0,64,...,448

    float* gio = io + (size_t)b * S_LEN * H_DIM + h0;

    float v = 0.f;
    float theta = 1.f;
    float tden = theta + EPS_F;
    float rseed = __builtin_amdgcn_rcpf(tden);
    float eseed = fmaf(-tden, rseed, 1.0f);
    float r0 = fmaf(eseed, rseed, rseed);
    float cl = 32.f * theta;
    const float kZero = 0.0f;
    const float kSixteen = 16.0f;

    stage_chunk(gio, &sbuf[0][0][0], 0, lane);
    asm volatile("s_waitcnt vmcnt(0)" ::: "memory");

    const int NCHUNK = S_LEN / 32;    // 128
    for (int c = 0; c < NCHUNK; ++c) {
        if (c + 1 < NCHUNK) {
            stage_chunk(gio, &sbuf[(c + 1) & 1][0][0], c + 1, lane);
            // outstanding: stage(c)=8, stores(c-1)=32, stage(c+1)=8 -> retire oldest 8.
            asm volatile("s_waitcnt vmcnt(40)" ::: "memory");
        } else {
            asm volatile("s_waitcnt vmcnt(32)" ::: "memory");
        }
        __builtin_amdgcn_sched_barrier(0);

        const float* sb = &sbuf[c & 1][0][lane];
        float* gout = gio + (size_t)c * 32 * H_DIM + lane;

        float rb[8];
#pragma unroll
        for (int i = 0; i < 8; ++i) rb[i] = sb[i * 64];

#pragma unroll
        for (int u = 0; u < 32; ++u) {
            const float it = rb[u & 7];
            if (u + 8 < 32) rb[u & 7] = sb[(u + 8) * 64];   // issue ds_read ~8 steps early

            v = v * DECAY_F + it;
            // v = clamp(v, -cl, cl), bit-exact (cl = 32*theta >= 0, v never NaN)
            asm("v_med3_f32 %0, %1, -%2, %2" : "=v"(v) : "v"(v), "v"(cl));

            // nv = v / tden, bit-identical IEEE div (Newton-Markstein, normals only):
            const float q0 = v * r0;
            const float e1 = fmaf(-tden, q0, v);
            const float q1 = fmaf(e1, r0, q0);
            const float e2 = fmaf(-tden, q1, v);
            const float nv = fmaf(e2, r0, q1);

            float spike = floorf(nv);
            // spike = clamp(spike, 0, 16), bit-exact
            asm("v_med3_f32 %0, %1, %2, %3" : "=v"(spike) : "v"(spike), "v"(kZero), "v"(kSixteen));

            v = v - spike * theta;
            theta = theta + ALPHA_F * spike - ALPHA_F * (theta - 1.0f);

            // off-critical-path: next step's denominator, reciprocal, clamp bound
            tden = theta + EPS_F;
            const float rr = __builtin_amdgcn_rcpf(tden);
            const float ee = fmaf(-tden, rr, 1.0f);
            r0 = fmaf(ee, rr, rr);
            cl = 32.f * theta;

            gout[(size_t)u * H_DIM] = spike;
            __builtin_amdgcn_sched_barrier(0);
        }
    }

    const int chain = b * H_DIM + h0 + lane;
    vout[chain]  = v;
    thout[chain] = theta;
}

extern "C" void kernel_launch(void* const* d_in, const int* in_sizes, int n_in,
                              void* d_out, int out_size, void* d_ws, size_t ws_size,
                              hipStream_t stream) {
    const float* x    = (const float*)d_in[0];
    const float* W    = (const float*)d_in[1];
    const float* bias = (const float*)d_in[2];

    float* out   = (float*)d_out;
    float* vout  = out + (size_t)B_DIM * S_LEN * H_DIM;
    float* thout = vout + B_DIM * H_DIM;

    dim3 grid(H_DIM / 128, (B_DIM * S_LEN) / 128);
    gemm_kernel<<<grid, 256, 0, stream>>>(x, W, bias, out);

    scan_kernel<<<64, 64, 0, stream>>>(out, vout, thout);
}